// Round 1
// baseline (209.479 us; speedup 1.0000x reference)
//
#include <hip/hip_runtime.h>
#include <math.h>

// TQUnitaryBuilder: 9-wire, 4-layer circuit -> U (512x512 real) per sample,
// fused with closed-form expm of the rank-2 skew matrix and the final matmul
// (which reduces to a rank-2 column correction on cols 0..71).
//
// State index convention: wire w lives at bit p(w)=8-w (bit8 = wire0 = MSB),
// matching eye(D).reshape(D,2,...,2). CNOT ring composed into one permutation:
// pre-perm source of post-perm index y is Finv(y) = (y ^ (y>>1)) ^ ((y&1)*0x180).
//
// ws layout (floats): per sample s, 384 floats at prep+s*384:
//   [0..287]  36 gates x 8 floats (g00r,g00i,g01r,g01i,g10r,g10i,g11r,g11i)
//   [288..359] v[72] (0.01*params, v[0]=0)
//   [360] cos(theta)  [361] alpha=sin(th)/th  [362] beta=(1-cos th)/th^2

__device__ __forceinline__ float2 cmul(float2 a, float2 b){
  return make_float2(fmaf(a.x, b.x, -a.y*b.y), fmaf(a.x, b.y, a.y*b.x));
}
__device__ __forceinline__ float2 cfma(float2 a, float2 b, float2 c){ // a*b + c
  return make_float2(fmaf(a.x, b.x, fmaf(-a.y, b.y, c.x)),
                     fmaf(a.x, b.y, fmaf( a.y, b.x, c.y)));
}

template<int STRIDE>
__device__ __forceinline__ void apply_gate(float2 amp[8], const float* g){
  const float2 g00 = make_float2(g[0], g[1]);
  const float2 g01 = make_float2(g[2], g[3]);
  const float2 g10 = make_float2(g[4], g[5]);
  const float2 g11 = make_float2(g[6], g[7]);
  #pragma unroll
  for (int b = 0; b < 8; ++b){
    if (b & STRIDE) continue;
    const float2 u = amp[b], v = amp[b + STRIDE];
    amp[b]          = cfma(g01, v, cmul(g00, u));
    amp[b + STRIDE] = cfma(g11, v, cmul(g10, u));
  }
}

// ---------------- kernel 1: MLP + gate/expm prep (tiny) ----------------
__global__ __launch_bounds__(256)
void prep_kernel(const float* __restrict__ t,  const float* __restrict__ w1,
                 const float* __restrict__ b1, const float* __restrict__ w2,
                 const float* __restrict__ b2, float* __restrict__ prep){
  __shared__ float sh[512];
  __shared__ float spar[72];
  const int s = blockIdx.x;
  const float ts = t[s];
  for (int k = threadIdx.x; k < 512; k += 256){
    const float z = fmaf(ts, w1[k], b1[k]);
    sh[k] = z / (1.f + expf(-z));            // silu
  }
  __syncthreads();
  if (threadIdx.x < 72){
    const int p = threadIdx.x;
    float acc = b2[p];
    for (int k = 0; k < 512; ++k) acc = fmaf(sh[k], w2[k*72 + p], acc);
    spar[p] = acc;
  }
  __syncthreads();
  float* pb = prep + s*384;
  if (threadIdx.x < 36){
    const int g = threadIdx.x;
    const float thy = spar[2*g], thz = spar[2*g + 1];
    float sn, c, zi, zr;
    sincosf(0.5f*thy, &sn, &c);
    sincosf(0.5f*thz, &zi, &zr);             // e = (zr, zi) = exp(i*thz/2)
    float* gq = pb + g*8;
    gq[0] =  zr*c;  gq[1] = -zi*c;           // g00 = conj(e)*c
    gq[2] = -zr*sn; gq[3] =  zi*sn;          // g01 = -conj(e)*s
    gq[4] =  zr*sn; gq[5] =  zi*sn;          // g10 = e*s
    gq[6] =  zr*c;  gq[7] =  zi*c;           // g11 = e*c
  }
  if (threadIdx.x < 72){
    const int j = threadIdx.x;
    pb[288 + j] = (j == 0) ? 0.f : 0.01f*spar[j];
  }
  __syncthreads();
  if (threadIdx.x == 0){
    float th2 = 0.f;
    for (int j = 1; j < 72; ++j){ const float v = 0.01f*spar[j]; th2 = fmaf(v, v, th2); }
    const float th = sqrtf(th2);
    float alpha, beta;
    if (th > 1e-6f){
      alpha = sinf(th)/th;
      const float s2 = sinf(0.5f*th);
      beta = 2.f*s2*s2/th2;                  // (1-cos)/th^2, stable
    } else { alpha = 1.f - th2/6.f; beta = 0.5f; }
    pb[360] = cosf(th);
    pb[361] = alpha;
    pb[362] = beta;
  }
}

// ---------------- kernel 2: circuit simulation -> out = U (raw) ----------------
// Grid: 64 samples x 64 col-blocks (8 columns each). Block 512 thr = 8 waves,
// one wave per column; 8 amps (float2) per lane; LDS per column padded:
// phys(x) = x + ((x>>6)<<2) -> round-2 stride-8 accesses become 2-way (free).
__global__ __launch_bounds__(512, 6)
void sim_kernel(const float* __restrict__ prep, float* __restrict__ out){
  __shared__ __align__(16) float2 st[8][544];
  __shared__ float sg[288];
  const int s    = blockIdx.x >> 6;
  const int cb   = blockIdx.x & 63;
  const int wid  = threadIdx.x >> 6;
  const int lane = threadIdx.x & 63;
  const int col  = cb*8 + wid;               // input basis state / U column
  {
    const float* gp = prep + s*384;
    for (int tt = threadIdx.x; tt < 288; tt += 512) sg[tt] = gp[tt];
  }
  __syncthreads();

  float2 amp[8];
  // ---- layer 1 rotations on basis state |col> : product state, O(D) ----
  {
    float2 base = make_float2(1.f, 0.f);
    #pragma unroll
    for (int w = 0; w < 6; ++w){
      const int xb = (lane >> (5 - w)) & 1;  // x bit p(w)=8-w  (lane = x>>3)
      const int ib = (col  >> (8 - w)) & 1;  // input bit of wire w
      const float* g = &sg[w*8 + (xb*2 + ib)*2];
      base = cmul(base, make_float2(g[0], g[1]));
    }
    const int i6 = (col >> 2) & 1, i7 = (col >> 1) & 1, i8 = col & 1;
    float2 G6[2], G7[2], G8[2];
    #pragma unroll
    for (int r = 0; r < 2; ++r){
      G6[r] = make_float2(sg[48 + (r*2 + i6)*2], sg[48 + (r*2 + i6)*2 + 1]);
      G7[r] = make_float2(sg[56 + (r*2 + i7)*2], sg[56 + (r*2 + i7)*2 + 1]);
      G8[r] = make_float2(sg[64 + (r*2 + i8)*2], sg[64 + (r*2 + i8)*2 + 1]);
    }
    #pragma unroll
    for (int j = 0; j < 8; ++j){
      const float2 tj = cmul(cmul(G6[(j>>2)&1], G7[(j>>1)&1]), G8[j&1]);
      amp[j] = cmul(base, tj);
    }
    const int pb = (lane << 3) + ((lane >> 3) << 2);   // phys(lane*8)
    float4* dst = (float4*)&st[wid][pb];
    dst[0] = make_float4(amp[0].x, amp[0].y, amp[1].x, amp[1].y);
    dst[1] = make_float4(amp[2].x, amp[2].y, amp[3].x, amp[3].y);
    dst[2] = make_float4(amp[4].x, amp[4].y, amp[5].x, amp[5].y);
    dst[3] = make_float4(amp[6].x, amp[6].y, amp[7].x, amp[7].y);
  }

  for (int L = 1; L < 4; ++L){
    const int gb = L*72;                     // gate float base for this layer
    // round 1: wires 6,7,8 (bits 2..0), prev layer's CNOT-ring perm folded in
    __syncthreads();
    #pragma unroll
    for (int j = 0; j < 8; ++j){
      const int x   = (lane << 3) | j;
      const int src = (x ^ (x >> 1)) ^ ((x & 1) ? 0x180 : 0);
      amp[j] = st[wid][src + ((src >> 6) << 2)];
    }
    __syncthreads();
    apply_gate<4>(amp, &sg[gb + 48]);        // wire 6 (bit 2)
    apply_gate<2>(amp, &sg[gb + 56]);        // wire 7 (bit 1)
    apply_gate<1>(amp, &sg[gb + 64]);        // wire 8 (bit 0)
    {
      const int pb = (lane << 3) + ((lane >> 3) << 2);
      float4* dst = (float4*)&st[wid][pb];
      dst[0] = make_float4(amp[0].x, amp[0].y, amp[1].x, amp[1].y);
      dst[1] = make_float4(amp[2].x, amp[2].y, amp[3].x, amp[3].y);
      dst[2] = make_float4(amp[4].x, amp[4].y, amp[5].x, amp[5].y);
      dst[3] = make_float4(amp[6].x, amp[6].y, amp[7].x, amp[7].y);
    }
    // round 2: wires 3,4,5 (bits 5..3); x = h<<6 | j<<3 | l, phys = 68h+8j+l
    __syncthreads();
    {
      const int b2 = (lane >> 3)*68 + (lane & 7);
      #pragma unroll
      for (int j = 0; j < 8; ++j) amp[j] = st[wid][b2 + j*8];
      apply_gate<4>(amp, &sg[gb + 24]);      // wire 3 (bit 5)
      apply_gate<2>(amp, &sg[gb + 32]);      // wire 4 (bit 4)
      apply_gate<1>(amp, &sg[gb + 40]);      // wire 5 (bit 3)
      #pragma unroll
      for (int j = 0; j < 8; ++j) st[wid][b2 + j*8] = amp[j];
    }
    // round 3: wires 0,1,2 (bits 8..6); x = j<<6 | lane, phys = 68j+lane
    __syncthreads();
    {
      #pragma unroll
      for (int j = 0; j < 8; ++j) amp[j] = st[wid][j*68 + lane];
      apply_gate<4>(amp, &sg[gb +  0]);      // wire 0 (bit 8)
      apply_gate<2>(amp, &sg[gb +  8]);      // wire 1 (bit 7)
      apply_gate<1>(amp, &sg[gb + 16]);      // wire 2 (bit 6)
      #pragma unroll
      for (int j = 0; j < 8; ++j) st[wid][j*68 + lane] = amp[j];
    }
  }
  __syncthreads();
  // transposed write of Re(state), final ring perm folded into the gather.
  // thread -> (row a, quad q): 64B.. 32B chunks per out row of this 8-col slice.
  #pragma unroll
  for (int rep = 0; rep < 2; ++rep){
    const int a   = (threadIdx.x >> 1) + rep*256;
    const int q   = threadIdx.x & 1;
    const int src = (a ^ (a >> 1)) ^ ((a & 1) ? 0x180 : 0);
    const int ps  = src + ((src >> 6) << 2);
    float4 vv;
    vv.x = st[q*4 + 0][ps].x;
    vv.y = st[q*4 + 1][ps].x;
    vv.z = st[q*4 + 2][ps].x;
    vv.w = st[q*4 + 3][ps].x;
    *(float4*)&out[(size_t)s*262144 + (size_t)a*512 + cb*8 + q*4] = vv;
  }
}

// ---------------- kernel 3: rank-2 expm correction on cols 0..71 ----------------
// out[:,0]   = cos(th)*u0 - alpha*(U v)
// out[:,j]   = U[:,j] + (alpha*u0 - beta*(U v)) * v[j]   (1<=j<72)
// Reads raw U from `out` (written by sim_kernel), rewrites in place per sample.
__global__ __launch_bounds__(256)
void corr_kernel(const float* __restrict__ prep, float* __restrict__ out){
  __shared__ float tile[128][73];
  __shared__ float sw_[128];
  __shared__ float suv[128][2];
  __shared__ float sv[72];
  const int s = blockIdx.x;
  const float* pp = prep + s*384;
  if (threadIdx.x < 72) sv[threadIdx.x] = pp[288 + threadIdx.x];
  const float cth   = pp[360];
  const float alpha = pp[361];
  const float beta  = pp[362];
  float* const ob = out + (size_t)s*262144;
  for (int t0 = 0; t0 < 512; t0 += 128){
    __syncthreads();                          // sv ready / tile reusable
    const int rr   = threadIdx.x >> 1;        // 0..127
    const int side = threadIdx.x & 1;
    const int r    = t0 + rr;
    const int j0   = side*36;
    float uvp = 0.f;
    for (int k = 0; k < 36; ++k){
      const int j = j0 + k;
      const float x = ob[r*512 + j];
      tile[rr][j] = x;
      uvp = fmaf(x, sv[j], uvp);              // v[0]=0 covers j=0
    }
    suv[rr][side] = uvp;
    __syncthreads();
    const float uv = suv[rr][0] + suv[rr][1];
    if (side == 0){
      const float u0 = tile[rr][0];
      sw_[rr] = fmaf(alpha, u0, -beta*uv);
      tile[rr][0] = cth*u0 - alpha*uv;
    }
    __syncthreads();
    const float w = sw_[rr];
    for (int k = 0; k < 36; ++k){
      const int j = j0 + k;
      if (j > 0) tile[rr][j] = fmaf(w, sv[j], tile[rr][j]);
    }
    __syncthreads();
    for (int idx = threadIdx.x; idx < 128*18; idx += 256){
      const int row = idx / 18, q = idx % 18;
      const float4 vv = make_float4(tile[row][q*4], tile[row][q*4+1],
                                    tile[row][q*4+2], tile[row][q*4+3]);
      *(float4*)&ob[(size_t)(t0 + row)*512 + q*4] = vv;
    }
  }
}

extern "C" void kernel_launch(void* const* d_in, const int* in_sizes, int n_in,
                              void* d_out, int out_size, void* d_ws, size_t ws_size,
                              hipStream_t stream){
  const float* t  = (const float*)d_in[0];
  const float* w1 = (const float*)d_in[1];
  const float* b1 = (const float*)d_in[2];
  const float* w2 = (const float*)d_in[3];
  const float* b2 = (const float*)d_in[4];
  float* out  = (float*)d_out;
  float* prep = (float*)d_ws;                 // 64*384 floats = 96 KiB used
  prep_kernel<<<64,   256, 0, stream>>>(t, w1, b1, w2, b2, prep);
  sim_kernel <<<4096, 512, 0, stream>>>(prep, out);
  corr_kernel<<<64,   256, 0, stream>>>(prep, out);
}

// Round 2
// 186.187 us; speedup vs baseline: 1.1251x; 1.1251x over previous
//
#include <hip/hip_runtime.h>
#include <math.h>

// TQUnitaryBuilder: 9-wire, 4-layer circuit -> U (512x512 real) per sample,
// fused with closed-form expm of the rank-2 skew matrix and the final matmul
// (rank-2 column correction on cols 0..71).
//
// x bit convention: wire w lives at bit 8-w. Ring CNOT perm (forward):
// y = F(x), y_k = XOR_{m>=k} x_m (k=0..7), y_8 = XOR_{m<=7} x_m.
// Its inverse is Finv(y) = y ^ (y>>1) ^ ((y&1)*0x180) (verified both ways).
// F and the LDS swizzle phys(x) = x ^ ((x>>4)&15) are GF(2)-linear, so all
// addresses decompose as lane_base ^ per-j compile-time constant.
//
// LDS swizzle gives exactly 4 lanes per bank-pair (b64 conflict-free
// baseline) for every access pattern used here:
//   linear  x = 8*lane + j          (R1 read/write, init logical layout)
//   R2      x = 64h + 8j + l        (lane = 8h + l)
//   R3 read x = 64j + lane
//   R3/init writes with ring fold   y = F(x)
//   output  x = a (linear)
//
// ws layout (floats): per sample s, 384 floats at prep+s*384:
//   [0..287]  36 gates x 8 floats (g00r,g00i,g01r,g01i,g10r,g10i,g11r,g11i)
//   [288..359] v[72] (0.01*params, v[0]=0)
//   [360] cos(theta)  [361] alpha=sin(th)/th  [362] beta=(1-cos th)/th^2

__device__ __forceinline__ float2 cmul(float2 a, float2 b){
  return make_float2(fmaf(a.x, b.x, -a.y*b.y), fmaf(a.x, b.y, a.y*b.x));
}
__device__ __forceinline__ float2 cfma(float2 a, float2 b, float2 c){ // a*b + c
  return make_float2(fmaf(a.x, b.x, fmaf(-a.y, b.y, c.x)),
                     fmaf(a.x, b.y, fmaf( a.y, b.x, c.y)));
}

__device__ __forceinline__ int Fperm(int x){       // forward ring permutation
  int S = x ^ (x >> 1); S ^= S >> 2; S ^= S >> 4; S ^= S >> 8;
  return (S & 0xFF) | ((((x >> 8) ^ S) & 1) << 8);
}
__device__ __forceinline__ int physmap(int x){ return x ^ ((x >> 4) & 15); }

template<int STRIDE>
__device__ __forceinline__ void apply_gate(float2 amp[8], const float* g){
  const float2 g00 = make_float2(g[0], g[1]);
  const float2 g01 = make_float2(g[2], g[3]);
  const float2 g10 = make_float2(g[4], g[5]);
  const float2 g11 = make_float2(g[6], g[7]);
  #pragma unroll
  for (int b = 0; b < 8; ++b){
    if (b & STRIDE) continue;
    const float2 u = amp[b], v = amp[b + STRIDE];
    amp[b]          = cfma(g01, v, cmul(g00, u));
    amp[b + STRIDE] = cfma(g11, v, cmul(g10, u));
  }
}

// ---------------- kernel 1: MLP + gate/expm prep (tiny) ----------------
__global__ __launch_bounds__(288)
void prep_kernel(const float* __restrict__ t,  const float* __restrict__ w1,
                 const float* __restrict__ b1, const float* __restrict__ w2,
                 const float* __restrict__ b2, float* __restrict__ prep){
  __shared__ float sh[512];
  __shared__ float part[4][72];
  __shared__ float spar[72];
  const int s = blockIdx.x;
  const float ts = t[s];
  for (int k = threadIdx.x; k < 512; k += 288){
    const float z = fmaf(ts, w1[k], b1[k]);
    sh[k] = z / (1.f + expf(-z));            // silu
  }
  __syncthreads();
  {
    const int p = threadIdx.x % 72, c = threadIdx.x / 72;   // c in 0..3
    float acc = 0.f;
    const int k0 = c*128;
    for (int k = k0; k < k0 + 128; ++k) acc = fmaf(sh[k], w2[k*72 + p], acc);
    part[c][p] = acc;
  }
  __syncthreads();
  if (threadIdx.x < 72){
    const int p = threadIdx.x;
    spar[p] = b2[p] + part[0][p] + part[1][p] + part[2][p] + part[3][p];
  }
  __syncthreads();
  float* pb = prep + s*384;
  if (threadIdx.x < 36){
    const int g = threadIdx.x;
    const float thy = spar[2*g], thz = spar[2*g + 1];
    float sn, c, zi, zr;
    sincosf(0.5f*thy, &sn, &c);
    sincosf(0.5f*thz, &zi, &zr);             // e = (zr, zi) = exp(i*thz/2)
    float* gq = pb + g*8;
    gq[0] =  zr*c;  gq[1] = -zi*c;           // g00 = conj(e)*c
    gq[2] = -zr*sn; gq[3] =  zi*sn;          // g01 = -conj(e)*s
    gq[4] =  zr*sn; gq[5] =  zi*sn;          // g10 = e*s
    gq[6] =  zr*c;  gq[7] =  zi*c;           // g11 = e*c
  }
  if (threadIdx.x < 72){
    const int j = threadIdx.x;
    pb[288 + j] = (j == 0) ? 0.f : 0.01f*spar[j];
  }
  __syncthreads();
  if (threadIdx.x == 0){
    float th2 = 0.f;
    for (int j = 1; j < 72; ++j){ const float v = 0.01f*spar[j]; th2 = fmaf(v, v, th2); }
    const float th = sqrtf(th2);
    float alpha, beta;
    if (th > 1e-6f){
      alpha = sinf(th)/th;
      const float s2 = sinf(0.5f*th);
      beta = 2.f*s2*s2/th2;                  // (1-cos)/th^2, stable
    } else { alpha = 1.f - th2/6.f; beta = 0.5f; }
    pb[360] = cosf(th);
    pb[361] = alpha;
    pb[362] = beta;
  }
}

// ---------------- kernel 2: circuit simulation -> out = U (raw) ----------------
// Grid: 64 samples x 64 col-blocks (8 columns each). Block 512 thr = 8 waves,
// one wave per column, st[wid] wave-private -> NO barriers in the layer loop.
__global__ __launch_bounds__(512, 8)
void sim_kernel(const float* __restrict__ prep, float* __restrict__ out){
  __shared__ __align__(16) float2 st[8][512];
  __shared__ __align__(16) float sg[288];
  const int s    = blockIdx.x >> 6;
  const int cb   = blockIdx.x & 63;
  const int wid  = threadIdx.x >> 6;
  const int lane = threadIdx.x & 63;
  const int col  = cb*8 + wid;               // input basis state / U column
  {
    const float* gp = prep + s*384;
    for (int tt = threadIdx.x; tt < 288; tt += 512) sg[tt] = gp[tt];
  }
  __syncthreads();                            // sg visible to all waves
  float2* const S = st[wid];

  float2 amp[8];
  // ---- layer 1 rotations on basis state |col> : product state, O(D) ----
  {
    float2 base = make_float2(1.f, 0.f);
    #pragma unroll
    for (int w = 0; w < 6; ++w){
      const int xb = (lane >> (5 - w)) & 1;  // x bit 8-w  (lane = x>>3)
      const int ib = (col  >> (8 - w)) & 1;  // input bit of wire w
      const float* g = &sg[w*8 + (xb*2 + ib)*2];
      base = cmul(base, make_float2(g[0], g[1]));
    }
    const int i6 = (col >> 2) & 1, i7 = (col >> 1) & 1, i8 = col & 1;
    float2 G6[2], G7[2], G8[2];
    #pragma unroll
    for (int r = 0; r < 2; ++r){
      G6[r] = make_float2(sg[48 + (r*2 + i6)*2], sg[48 + (r*2 + i6)*2 + 1]);
      G7[r] = make_float2(sg[56 + (r*2 + i7)*2], sg[56 + (r*2 + i7)*2 + 1]);
      G8[r] = make_float2(sg[64 + (r*2 + i8)*2], sg[64 + (r*2 + i8)*2 + 1]);
    }
    #pragma unroll
    for (int j = 0; j < 8; ++j){
      const float2 tj = cmul(cmul(G6[(j>>2)&1], G7[(j>>1)&1]), G8[j&1]);
      amp[j] = cmul(base, tj);
    }
    // write with ring-1 folded: element x = 8*lane + j -> slot phys(F(x))
    const int bFI = physmap(Fperm(lane << 3));
    #pragma unroll
    for (int j = 0; j < 8; ++j) S[bFI ^ physmap(Fperm(j))] = amp[j];
  }

  const int base1 = (lane << 3) ^ ((lane >> 1) & 15);            // phys(8*lane)
  const int hq = lane >> 3, lq = lane & 7;
  const int base2 = (hq << 6) ^ ((hq << 2) & 15) ^ lq;           // phys(64h)^l
  const int base3 = lane ^ (lane >> 4);                          // phys(lane)
  const int baseF = physmap(Fperm(lane));

  #pragma unroll
  for (int L = 1; L < 4; ++L){
    const int gb = L*72;
    // round 1: wires 6,7,8 (x bits 2..0) — linear read (ring already folded)
    #pragma unroll
    for (int j = 0; j < 8; ++j) amp[j] = S[base1 ^ j];
    apply_gate<4>(amp, &sg[gb + 48]);        // wire 6 (bit 2)
    apply_gate<2>(amp, &sg[gb + 56]);        // wire 7 (bit 1)
    apply_gate<1>(amp, &sg[gb + 64]);        // wire 8 (bit 0)
    #pragma unroll
    for (int j = 0; j < 8; ++j) S[base1 ^ j] = amp[j];
    // round 2: wires 3,4,5 (x bits 5..3); x = 64h + 8j + l
    #pragma unroll
    for (int j = 0; j < 8; ++j) amp[j] = S[base2 ^ ((j << 3) ^ (j >> 1))];
    apply_gate<4>(amp, &sg[gb + 24]);        // wire 3 (bit 5)
    apply_gate<2>(amp, &sg[gb + 32]);        // wire 4 (bit 4)
    apply_gate<1>(amp, &sg[gb + 40]);        // wire 5 (bit 3)
    #pragma unroll
    for (int j = 0; j < 8; ++j) S[base2 ^ ((j << 3) ^ (j >> 1))] = amp[j];
    // round 3: wires 0,1,2 (x bits 8..6); x = 64j + lane
    #pragma unroll
    for (int j = 0; j < 8; ++j) amp[j] = S[base3 ^ ((j << 6) ^ ((4*j) & 15))];
    apply_gate<4>(amp, &sg[gb +  0]);        // wire 0 (bit 8)
    apply_gate<2>(amp, &sg[gb +  8]);        // wire 1 (bit 7)
    apply_gate<1>(amp, &sg[gb + 16]);        // wire 2 (bit 6)
    // write with this layer's ring folded: x = 64j + lane -> phys(F(x))
    #pragma unroll
    for (int j = 0; j < 8; ++j) S[baseF ^ physmap(Fperm(j << 6))] = amp[j];
  }

  __syncthreads();                            // output reads other waves' arrays
  // transposed write of Re(state); state fully permuted -> linear element a.
  #pragma unroll
  for (int rep = 0; rep < 2; ++rep){
    const int a  = (threadIdx.x >> 1) + rep*256;
    const int q  = threadIdx.x & 1;
    const int pa = a ^ ((a >> 4) & 15);
    float4 vv;
    vv.x = st[q*4 + 0][pa].x;
    vv.y = st[q*4 + 1][pa].x;
    vv.z = st[q*4 + 2][pa].x;
    vv.w = st[q*4 + 3][pa].x;
    *(float4*)&out[(size_t)s*262144 + (size_t)a*512 + cb*8 + q*4] = vv;
  }
}

// ---------------- kernel 3: rank-2 expm correction on cols 0..71 ----------------
// out[:,0]   = cos(th)*u0 - alpha*(U v)
// out[:,j]   = U[:,j] + (alpha*u0 - beta*(U v)) * v[j]   (1<=j<72)
__global__ __launch_bounds__(256)
void corr_kernel(const float* __restrict__ prep, float* __restrict__ out){
  __shared__ float tile[128][73];
  __shared__ float sw_[128];
  __shared__ float suv[128][2];
  __shared__ float sv[72];
  const int s = blockIdx.x;
  const float* pp = prep + s*384;
  if (threadIdx.x < 72) sv[threadIdx.x] = pp[288 + threadIdx.x];
  const float cth   = pp[360];
  const float alpha = pp[361];
  const float beta  = pp[362];
  float* const ob = out + (size_t)s*262144;
  for (int t0 = 0; t0 < 512; t0 += 128){
    __syncthreads();                          // sv ready / tile reusable
    const int rr   = threadIdx.x >> 1;        // 0..127
    const int side = threadIdx.x & 1;
    const int r    = t0 + rr;
    const int j0   = side*36;
    float uvp = 0.f;
    for (int k = 0; k < 36; ++k){
      const int j = j0 + k;
      const float x = ob[r*512 + j];
      tile[rr][j] = x;
      uvp = fmaf(x, sv[j], uvp);              // v[0]=0 covers j=0
    }
    suv[rr][side] = uvp;
    __syncthreads();
    const float uv = suv[rr][0] + suv[rr][1];
    if (side == 0){
      const float u0 = tile[rr][0];
      sw_[rr] = fmaf(alpha, u0, -beta*uv);
      tile[rr][0] = cth*u0 - alpha*uv;
    }
    __syncthreads();
    const float w = sw_[rr];
    for (int k = 0; k < 36; ++k){
      const int j = j0 + k;
      if (j > 0) tile[rr][j] = fmaf(w, sv[j], tile[rr][j]);
    }
    __syncthreads();
    for (int idx = threadIdx.x; idx < 128*18; idx += 256){
      const int row = idx / 18, q = idx % 18;
      const float4 vv = make_float4(tile[row][q*4], tile[row][q*4+1],
                                    tile[row][q*4+2], tile[row][q*4+3]);
      *(float4*)&ob[(size_t)(t0 + row)*512 + q*4] = vv;
    }
  }
}

extern "C" void kernel_launch(void* const* d_in, const int* in_sizes, int n_in,
                              void* d_out, int out_size, void* d_ws, size_t ws_size,
                              hipStream_t stream){
  const float* t  = (const float*)d_in[0];
  const float* w1 = (const float*)d_in[1];
  const float* b1 = (const float*)d_in[2];
  const float* w2 = (const float*)d_in[3];
  const float* b2 = (const float*)d_in[4];
  float* out  = (float*)d_out;
  float* prep = (float*)d_ws;                 // 64*384 floats = 96 KiB used
  prep_kernel<<<64,   288, 0, stream>>>(t, w1, b1, w2, b2, prep);
  sim_kernel <<<4096, 512, 0, stream>>>(prep, out);
  corr_kernel<<<64,   256, 0, stream>>>(prep, out);
}

// Round 3
// 172.753 us; speedup vs baseline: 1.2126x; 1.0778x over previous
//
#include <hip/hip_runtime.h>
#include <math.h>

// TQUnitaryBuilder: 9-wire, 4-layer circuit -> U (512x512 real) per sample,
// fused with closed-form expm of the rank-2 skew matrix and the final matmul
// (rank-2 column correction on cols 0..71).
//
// x bit convention: wire w lives at bit 8-w. Ring CNOT perm (forward):
// y = F(x), y_k = XOR_{m>=k,m<=7} x_m (k<=7), y_8 = x_8 ^ y_0.
// F and the LDS swizzle phys(x) = x ^ ((x>>4)&15) are GF(2)-linear.
//
// Gate math uses packed fp32 (v_pk_fma_f32, full-rate on CDNA): complex
// g*u = u.x*P + u.y*Q with P=(re,im), Q=(-im,re) precomputed in prep.
//
// ws layout (floats): per sample s, 768 floats at prep+s*768:
//   [0..575]  36 gates x 16 floats: P00,Q00,P01,Q01,P10,Q10,P11,Q11 (float2 each)
//   [576..647] v[72] (0.01*params, v[0]=0)
//   [648] cos(theta)  [649] alpha=sin(th)/th  [650] beta=(1-cos th)/th^2

__device__ __forceinline__ float2 cmul(float2 a, float2 b){
  return make_float2(fmaf(a.x, b.x, -a.y*b.y), fmaf(a.x, b.y, a.y*b.x));
}

// packed fp32 helpers: d = bcast(a.x or a.y) * b + c, element-wise on float2
__device__ __forceinline__ float2 pk_fma_lo(float2 a, float2 b, float2 c){
  float2 d;
  asm("v_pk_fma_f32 %0, %1, %2, %3 op_sel:[0,0,0] op_sel_hi:[0,1,1]"
      : "=v"(d) : "v"(a), "v"(b), "v"(c));
  return d;
}
__device__ __forceinline__ float2 pk_fma_hi(float2 a, float2 b, float2 c){
  float2 d;
  asm("v_pk_fma_f32 %0, %1, %2, %3 op_sel:[1,0,0] op_sel_hi:[1,1,1]"
      : "=v"(d) : "v"(a), "v"(b), "v"(c));
  return d;
}
__device__ __forceinline__ float2 pk_mul_hi(float2 a, float2 b){
  float2 d;
  asm("v_pk_mul_f32 %0, %1, %2 op_sel:[1,0] op_sel_hi:[1,1]"
      : "=v"(d) : "v"(a), "v"(b));
  return d;
}

__device__ __forceinline__ int Fperm(int x){       // forward ring permutation
  int S = x ^ (x >> 1); S ^= S >> 2; S ^= S >> 4; S ^= S >> 8;
  return (S & 0xFF) | ((((x >> 8) ^ S) & 1) << 8);
}
__device__ __forceinline__ int physmap(int x){ return x ^ ((x >> 4) & 15); }

template<int STRIDE>
__device__ __forceinline__ void apply_gate_pk(float2 amp[8], const float4* gq){
  const float4 a0 = gq[0], a1 = gq[1], a2 = gq[2], a3 = gq[3];
  const float2 P00 = make_float2(a0.x,a0.y), Q00 = make_float2(a0.z,a0.w);
  const float2 P01 = make_float2(a1.x,a1.y), Q01 = make_float2(a1.z,a1.w);
  const float2 P10 = make_float2(a2.x,a2.y), Q10 = make_float2(a2.z,a2.w);
  const float2 P11 = make_float2(a3.x,a3.y), Q11 = make_float2(a3.z,a3.w);
  #pragma unroll
  for (int b = 0; b < 8; ++b){
    if (b & STRIDE) continue;
    const float2 u = amp[b], v = amp[b + STRIDE];
    amp[b]          = pk_fma_lo(u,P00, pk_fma_hi(u,Q00, pk_fma_lo(v,P01, pk_mul_hi(v,Q01))));
    amp[b + STRIDE] = pk_fma_lo(u,P10, pk_fma_hi(u,Q10, pk_fma_lo(v,P11, pk_mul_hi(v,Q11))));
  }
}

// ---------------- kernel 1: MLP + gate/expm prep (tiny) ----------------
__global__ __launch_bounds__(576)
void prep_kernel(const float* __restrict__ t,  const float* __restrict__ w1,
                 const float* __restrict__ b1, const float* __restrict__ w2,
                 const float* __restrict__ b2, float* __restrict__ prep){
  __shared__ float sh[512];
  __shared__ float part[8][72];
  __shared__ float spar[72];
  const int s = blockIdx.x;
  const float ts = t[s];
  for (int k = threadIdx.x; k < 512; k += 576){
    const float z = fmaf(ts, w1[k], b1[k]);
    sh[k] = z / (1.f + expf(-z));            // silu
  }
  __syncthreads();
  {
    const int p = threadIdx.x % 72, c = threadIdx.x / 72;   // c in 0..7
    float acc = 0.f;
    const int k0 = c*64;
    for (int k = k0; k < k0 + 64; ++k) acc = fmaf(sh[k], w2[k*72 + p], acc);
    part[c][p] = acc;
  }
  __syncthreads();
  if (threadIdx.x < 72){
    const int p = threadIdx.x;
    float acc = b2[p];
    #pragma unroll
    for (int c = 0; c < 8; ++c) acc += part[c][p];
    spar[p] = acc;
  }
  __syncthreads();
  float* pb = prep + s*768;
  if (threadIdx.x < 36){
    const int g = threadIdx.x;
    const float thy = spar[2*g], thz = spar[2*g + 1];
    float sy, cy, zi, zr;
    sincosf(0.5f*thy, &sy, &cy);
    sincosf(0.5f*thz, &zi, &zr);             // e = (zr, zi) = exp(i*thz/2)
    float4* gq = (float4*)(pb + g*16);
    // g00 = conj(e)*cy = ( zr*cy, -zi*cy)
    gq[0] = make_float4( zr*cy, -zi*cy,  zi*cy,  zr*cy);
    // g01 = -conj(e)*sy = (-zr*sy,  zi*sy)
    gq[1] = make_float4(-zr*sy,  zi*sy, -zi*sy, -zr*sy);
    // g10 = e*sy = ( zr*sy,  zi*sy)
    gq[2] = make_float4( zr*sy,  zi*sy, -zi*sy,  zr*sy);
    // g11 = e*cy = ( zr*cy,  zi*cy)
    gq[3] = make_float4( zr*cy,  zi*cy, -zi*cy,  zr*cy);
  }
  if (threadIdx.x >= 64 && threadIdx.x < 136){
    const int j = threadIdx.x - 64;
    pb[576 + j] = (j == 0) ? 0.f : 0.01f*spar[j];
  }
  if (threadIdx.x == 0){
    float th2 = 0.f;
    for (int j = 1; j < 72; ++j){ const float v = 0.01f*spar[j]; th2 = fmaf(v, v, th2); }
    const float th = sqrtf(th2);
    float alpha, beta;
    if (th > 1e-6f){
      alpha = sinf(th)/th;
      const float s2 = sinf(0.5f*th);
      beta = 2.f*s2*s2/th2;                  // (1-cos)/th^2, stable
    } else { alpha = 1.f - th2/6.f; beta = 0.5f; }
    pb[648] = cosf(th);
    pb[649] = alpha;
    pb[650] = beta;
  }
}

// ---------------- kernel 2: circuit simulation -> out = U (raw) ----------------
// Grid: blockIdx = cb*64 + s so the two blocks sharing each 64B output line
// (cb even/odd pair) are 64 apart -> same XCD under round-robin dispatch.
// Block 512 thr = 8 waves, one wave per column, st[wid] wave-private ->
// no barriers in the layer loop. Gates read from global with uniform
// addresses (scalar loads), LDS holds only the state.
__global__ __launch_bounds__(512, 6)
void sim_kernel(const float* __restrict__ prep, float* __restrict__ out){
  __shared__ __align__(16) float2 st[8][512];
  const int s    = blockIdx.x & 63;
  const int cb   = blockIdx.x >> 6;
  const int wid  = threadIdx.x >> 6;
  const int lane = threadIdx.x & 63;
  const int col  = cb*8 + wid;               // input basis state / U column
  const float* gp = prep + s*768;
  float2* const S = st[wid];

  float2 amp[8];
  // ---- layer 1 rotations on basis state |col> : product state, O(D) ----
  {
    float2 base = make_float2(1.f, 0.f);
    #pragma unroll
    for (int w = 0; w < 6; ++w){
      const int xb = (lane >> (5 - w)) & 1;  // x bit 8-w  (lane = x>>3)
      const int ib = (col  >> (8 - w)) & 1;  // input bit of wire w
      const float2 ge = *(const float2*)(gp + 16*w + (xb*2 + ib)*4);
      base = cmul(base, ge);
    }
    const int i6 = (col >> 2) & 1, i7 = (col >> 1) & 1, i8 = col & 1;
    float2 G6[2], G7[2], G8[2];
    #pragma unroll
    for (int r = 0; r < 2; ++r){
      G6[r] = *(const float2*)(gp + 16*6 + (r*2 + i6)*4);
      G7[r] = *(const float2*)(gp + 16*7 + (r*2 + i7)*4);
      G8[r] = *(const float2*)(gp + 16*8 + (r*2 + i8)*4);
    }
    #pragma unroll
    for (int j = 0; j < 8; ++j){
      const float2 tj = cmul(cmul(G6[(j>>2)&1], G7[(j>>1)&1]), G8[j&1]);
      amp[j] = cmul(base, tj);
    }
    // write with ring-1 folded: element x = 8*lane + j -> slot phys(F(x))
    const int bFI = physmap(Fperm(lane << 3));
    #pragma unroll
    for (int j = 0; j < 8; ++j) S[bFI ^ physmap(Fperm(j))] = amp[j];
  }

  const int base1 = (lane << 3) ^ ((lane >> 1) & 15);            // phys(8*lane)
  const int hq = lane >> 3, lq = lane & 7;
  const int base2 = (hq << 6) ^ ((hq << 2) & 15) ^ lq;           // phys(64h)^l
  const int base3 = lane ^ (lane >> 4);                          // phys(lane)
  const int baseF = physmap(Fperm(lane));

  #pragma unroll
  for (int L = 1; L < 4; ++L){
    const float* gl = gp + L*9*16;
    // round 1: wires 6,7,8 (x bits 2..0) — linear read (ring already folded)
    #pragma unroll
    for (int j = 0; j < 8; ++j) amp[j] = S[base1 ^ j];
    apply_gate_pk<4>(amp, (const float4*)(gl + 6*16));   // wire 6 (bit 2)
    apply_gate_pk<2>(amp, (const float4*)(gl + 7*16));   // wire 7 (bit 1)
    apply_gate_pk<1>(amp, (const float4*)(gl + 8*16));   // wire 8 (bit 0)
    #pragma unroll
    for (int j = 0; j < 8; ++j) S[base1 ^ j] = amp[j];
    // round 2: wires 3,4,5 (x bits 5..3); x = 64h + 8j + l
    #pragma unroll
    for (int j = 0; j < 8; ++j) amp[j] = S[base2 ^ ((j << 3) ^ (j >> 1))];
    apply_gate_pk<4>(amp, (const float4*)(gl + 3*16));   // wire 3 (bit 5)
    apply_gate_pk<2>(amp, (const float4*)(gl + 4*16));   // wire 4 (bit 4)
    apply_gate_pk<1>(amp, (const float4*)(gl + 5*16));   // wire 5 (bit 3)
    #pragma unroll
    for (int j = 0; j < 8; ++j) S[base2 ^ ((j << 3) ^ (j >> 1))] = amp[j];
    // round 3: wires 0,1,2 (x bits 8..6); x = 64j + lane
    #pragma unroll
    for (int j = 0; j < 8; ++j) amp[j] = S[base3 ^ ((j << 6) ^ ((4*j) & 15))];
    apply_gate_pk<4>(amp, (const float4*)(gl + 0*16));   // wire 0 (bit 8)
    apply_gate_pk<2>(amp, (const float4*)(gl + 1*16));   // wire 1 (bit 7)
    apply_gate_pk<1>(amp, (const float4*)(gl + 2*16));   // wire 2 (bit 6)
    // write with this layer's ring folded: x = 64j + lane -> phys(F(x))
    #pragma unroll
    for (int j = 0; j < 8; ++j) S[baseF ^ physmap(Fperm(j << 6))] = amp[j];
  }

  __syncthreads();                            // output reads other waves' arrays
  // transposed write of Re(state); state fully permuted -> linear element a.
  #pragma unroll
  for (int rep = 0; rep < 2; ++rep){
    const int a  = (threadIdx.x >> 1) + rep*256;
    const int q  = threadIdx.x & 1;
    const int pa = a ^ ((a >> 4) & 15);
    float4 vv;
    vv.x = st[q*4 + 0][pa].x;
    vv.y = st[q*4 + 1][pa].x;
    vv.z = st[q*4 + 2][pa].x;
    vv.w = st[q*4 + 3][pa].x;
    *(float4*)&out[(size_t)s*262144 + (size_t)a*512 + cb*8 + q*4] = vv;
  }
}

// ---------------- kernel 3: rank-2 expm correction on cols 0..71 ----------------
// out[:,0]   = cos(th)*u0 - alpha*(U v)
// out[:,j]   = U[:,j] + (alpha*u0 - beta*(U v)) * v[j]   (1<=j<72)
// Grid: 64 samples x 32 row-groups of 16 rows; thread = (row, float4-quad).
__global__ __launch_bounds__(288)
void corr_kernel(const float* __restrict__ prep, float* __restrict__ out){
  __shared__ float part[16][18];
  __shared__ float srow[16][2];               // [0]=w, [1]=new col0 value
  const int s  = blockIdx.x >> 5;
  const int rg = blockIdx.x & 31;
  const float* pp = prep + s*768;
  const int lr = threadIdx.x / 18;            // 0..15
  const int q  = threadIdx.x - lr*18;         // 0..17
  float* rowp = out + (size_t)s*262144 + (size_t)(rg*16 + lr)*512;
  const float4 x  = *(const float4*)(rowp + q*4);
  const float4 vv = *(const float4*)(pp + 576 + q*4);
  part[lr][q] = fmaf(x.x,vv.x, fmaf(x.y,vv.y, fmaf(x.z,vv.z, x.w*vv.w)));
  __syncthreads();
  if (threadIdx.x < 16){
    const int row = threadIdx.x;
    float uv = 0.f;
    #pragma unroll
    for (int k = 0; k < 18; ++k) uv += part[row][k];
    const float u0 = out[(size_t)s*262144 + (size_t)(rg*16 + row)*512];
    const float cth = pp[648], alpha = pp[649], beta = pp[650];
    srow[row][0] = fmaf(alpha, u0, -beta*uv);
    srow[row][1] = cth*u0 - alpha*uv;
  }
  __syncthreads();
  const float w = srow[lr][0];
  float4 o;
  o.x = fmaf(w, vv.x, x.x); o.y = fmaf(w, vv.y, x.y);
  o.z = fmaf(w, vv.z, x.z); o.w = fmaf(w, vv.w, x.w);
  if (q == 0) o.x = srow[lr][1];              // v[0]=0, so fma left x.x; replace
  *(float4*)(rowp + q*4) = o;
}

extern "C" void kernel_launch(void* const* d_in, const int* in_sizes, int n_in,
                              void* d_out, int out_size, void* d_ws, size_t ws_size,
                              hipStream_t stream){
  const float* t  = (const float*)d_in[0];
  const float* w1 = (const float*)d_in[1];
  const float* b1 = (const float*)d_in[2];
  const float* w2 = (const float*)d_in[3];
  const float* b2 = (const float*)d_in[4];
  float* out  = (float*)d_out;
  float* prep = (float*)d_ws;                 // 64*768 floats = 192 KiB used
  prep_kernel<<<64,   576, 0, stream>>>(t, w1, b1, w2, b2, prep);
  sim_kernel <<<4096, 512, 0, stream>>>(prep, out);
  corr_kernel<<<2048, 288, 0, stream>>>(prep, out);
}

// Round 4
// 148.656 us; speedup vs baseline: 1.4092x; 1.1621x over previous
//
#include <hip/hip_runtime.h>
#include <math.h>

// TQUnitaryBuilder: 9-wire, 4-layer circuit -> U (512x512 real) per sample,
// fused with closed-form expm of the rank-2 skew matrix and the final matmul
// (rank-2 column correction on cols 0..71).
//
// x bit convention: wire w lives at bit 8-w. Ring CNOT perm F (forward):
// y_k = XOR_{m>=k,m<=7} x_m (k<=7), y_8 = x_8 ^ parity. LDS swizzle
// phys(x) = x ^ ((x>>4)&15); both GF(2)-linear.
//
// Gate factorization: G_w = diag(conj(e_w), e_w) * [[c,-s],[s,c]]. Diagonal
// phases on distinct wires commute with all rotations of the layer, so each
// layer = 9 real rotations (pk fp32, coeffs as SGPR operands) + ONE diagonal
// phase pass D(x) = B[x>>6] * A[x&63], applied in round 3 before the perm
// write. Layer 1 acts on a basis state -> product-state init with full gates.
//
// ws layout (floats): per sample s, stride 1024 at prep + s*1024:
//   [0..71]    layer-1 plain gates: 9 x {g00r,g00i,g01r,g01i,g10r,g10i,g11r,g11i}
//   per layer l=0..2 at base lb = 128 + l*256:
//     [lb+0..35]    rot coeffs: 9 wires x {c, -s, s, c}
//     [lb+64..95]   B-phase:    8 j x {Br, Bi, -Bi, Br}   (P,Q form)
//     [lb+128..255] A-phase:    64 m x {Ar, Ai}
//   [896..967] v[72] (0.01*params, v[0]=0)
//   [968] cos(theta)  [969] alpha=sin(th)/th  [970] beta=(1-cos th)/th^2

__device__ __forceinline__ float2 cmul(float2 a, float2 b){
  return make_float2(fmaf(a.x, b.x, -a.y*b.y), fmaf(a.x, b.y, a.y*b.x));
}

// ---- packed fp32 helpers (v_pk_fma_f32 / v_pk_mul_f32, full-rate) ----
// rot coeffs come in as SGPR pairs (one scalar source per VOP3P allowed).
__device__ __forceinline__ float2 pk_fma_s_lo(float2 s2, float2 b, float2 c){
  float2 d;  // d = s2.x * b + c
  asm("v_pk_fma_f32 %0, %1, %2, %3 op_sel:[0,0,0] op_sel_hi:[0,1,1]"
      : "=v"(d) : "s"(s2), "v"(b), "v"(c));
  return d;
}
__device__ __forceinline__ float2 pk_mul_s_hi(float2 s2, float2 b){
  float2 d;  // d = s2.y * b
  asm("v_pk_mul_f32 %0, %1, %2 op_sel:[1,0] op_sel_hi:[1,1]"
      : "=v"(d) : "s"(s2), "v"(b));
  return d;
}
__device__ __forceinline__ float2 pk_fma_vs_lo(float2 a, float2 b, float2 c){
  float2 d;  // d = a.x * b + c   (a VGPR, b SGPR)
  asm("v_pk_fma_f32 %0, %1, %2, %3 op_sel:[0,0,0] op_sel_hi:[0,1,1]"
      : "=v"(d) : "v"(a), "s"(b), "v"(c));
  return d;
}
__device__ __forceinline__ float2 pk_mul_vs_hi(float2 a, float2 b){
  float2 d;  // d = a.y * b
  asm("v_pk_mul_f32 %0, %1, %2 op_sel:[1,0] op_sel_hi:[1,1]"
      : "=v"(d) : "v"(a), "s"(b));
  return d;
}
__device__ __forceinline__ float2 pk_fma_vv_lo(float2 a, float2 b, float2 c){
  float2 d;  // d = a.x * b + c
  asm("v_pk_fma_f32 %0, %1, %2, %3 op_sel:[0,0,0] op_sel_hi:[0,1,1]"
      : "=v"(d) : "v"(a), "v"(b), "v"(c));
  return d;
}
__device__ __forceinline__ float2 pk_mul_vv_hi(float2 a, float2 b){
  float2 d;  // d = a.y * b
  asm("v_pk_mul_f32 %0, %1, %2 op_sel:[1,0] op_sel_hi:[1,1]"
      : "=v"(d) : "v"(a), "v"(b));
  return d;
}
__device__ __forceinline__ float2 pk_swapneg(float2 c, float2 n){
  float2 d;  // d = (-c.y, c.x)   with n = (-1, 1)
  asm("v_pk_mul_f32 %0, %1, %2 op_sel:[1,0] op_sel_hi:[0,1]"
      : "=v"(d) : "v"(c), "v"(n));
  return d;
}

__device__ __forceinline__ int Fperm(int x){       // forward ring permutation
  int S = x ^ (x >> 1); S ^= S >> 2; S ^= S >> 4; S ^= S >> 8;
  return (S & 0xFF) | ((((x >> 8) ^ S) & 1) << 8);
}
__device__ __forceinline__ int physmap(int x){ return x ^ ((x >> 4) & 15); }

template<int STRIDE>
__device__ __forceinline__ void apply_rot(float2 amp[8], const float2* rp){
  const float2 R0 = rp[0];                   // (c, -s)
  const float2 R1 = rp[1];                   // (s,  c)
  #pragma unroll
  for (int b = 0; b < 8; ++b){
    if (b & STRIDE) continue;
    const float2 u = amp[b], v = amp[b + STRIDE];
    amp[b]          = pk_fma_s_lo(R0, u, pk_mul_s_hi(R0, v));  // c*u - s*v
    amp[b + STRIDE] = pk_fma_s_lo(R1, u, pk_mul_s_hi(R1, v));  // s*u + c*v
  }
}

// ---------------- kernel 1: MLP + gate/phase/expm prep (tiny) ----------------
__global__ __launch_bounds__(576)
void prep_kernel(const float* __restrict__ t,  const float* __restrict__ w1,
                 const float* __restrict__ b1, const float* __restrict__ w2,
                 const float* __restrict__ b2, float* __restrict__ prep){
  __shared__ float sh[512];
  __shared__ float part[8][72];
  __shared__ float spar[72];
  const int s = blockIdx.x;
  const float ts = t[s];
  for (int k = threadIdx.x; k < 512; k += 576){
    const float z = fmaf(ts, w1[k], b1[k]);
    sh[k] = z / (1.f + expf(-z));            // silu
  }
  __syncthreads();
  {
    const int p = threadIdx.x % 72, c = threadIdx.x / 72;   // c in 0..7
    float acc = 0.f;
    const int k0 = c*64;
    for (int k = k0; k < k0 + 64; ++k) acc = fmaf(sh[k], w2[k*72 + p], acc);
    part[c][p] = acc;
  }
  __syncthreads();
  if (threadIdx.x < 72){
    const int p = threadIdx.x;
    float acc = b2[p];
    #pragma unroll
    for (int c = 0; c < 8; ++c) acc += part[c][p];
    spar[p] = acc;
  }
  __syncthreads();
  float* pb = prep + s*1024;
  const int tid = threadIdx.x;
  if (tid < 192){                            // A[64] per layer l=0..2
    const int l = tid >> 6, m = tid & 63;
    float2 acc = make_float2(1.f, 0.f);
    #pragma unroll
    for (int w = 3; w < 9; ++w){
      const float thz = spar[2*(9*(l+1) + w) + 1];
      float zi, zr; sincosf(0.5f*thz, &zi, &zr);
      const int bit = (m >> (8 - w)) & 1;
      acc = cmul(acc, make_float2(zr, bit ? zi : -zi));
    }
    pb[128 + l*256 + 128 + m*2]     = acc.x;
    pb[128 + l*256 + 128 + m*2 + 1] = acc.y;
  } else if (tid < 216){                     // B[8] per layer (P,Q form)
    const int q = tid - 192, l = q >> 3, j = q & 7;
    float2 acc = make_float2(1.f, 0.f);
    #pragma unroll
    for (int w = 0; w < 3; ++w){
      const float thz = spar[2*(9*(l+1) + w) + 1];
      float zi, zr; sincosf(0.5f*thz, &zi, &zr);
      const int bit = (j >> (2 - w)) & 1;
      acc = cmul(acc, make_float2(zr, bit ? zi : -zi));
    }
    float* o = pb + 128 + l*256 + 64 + j*4;
    o[0] = acc.x; o[1] = acc.y; o[2] = -acc.y; o[3] = acc.x;
  } else if (tid < 243){                     // rot coeffs, layers 2..4
    const int q = tid - 216, l = q / 9, w = q - l*9;
    const float thy = spar[2*(9*(l+1) + w)];
    float sy, cy; sincosf(0.5f*thy, &sy, &cy);
    float* o = pb + 128 + l*256 + w*4;
    o[0] = cy; o[1] = -sy; o[2] = sy; o[3] = cy;
  } else if (tid < 252){                     // layer-1 plain gates
    const int w = tid - 243;
    const float thy = spar[2*w], thz = spar[2*w + 1];
    float sy, cy, zi, zr;
    sincosf(0.5f*thy, &sy, &cy);
    sincosf(0.5f*thz, &zi, &zr);             // e = (zr, zi)
    float* o = pb + w*8;
    o[0] =  zr*cy; o[1] = -zi*cy;            // g00 = conj(e)*c
    o[2] = -zr*sy; o[3] =  zi*sy;            // g01 = -conj(e)*s
    o[4] =  zr*sy; o[5] =  zi*sy;            // g10 = e*s
    o[6] =  zr*cy; o[7] =  zi*cy;            // g11 = e*c
  } else if (tid < 324){                     // v[72]
    const int j = tid - 252;
    pb[896 + j] = (j == 0) ? 0.f : 0.01f*spar[j];
  } else if (tid == 324){                    // expm scalars
    float th2 = 0.f;
    for (int j = 1; j < 72; ++j){ const float v = 0.01f*spar[j]; th2 = fmaf(v, v, th2); }
    const float th = sqrtf(th2);
    float alpha, beta;
    if (th > 1e-6f){
      alpha = sinf(th)/th;
      const float s2 = sinf(0.5f*th);
      beta = 2.f*s2*s2/th2;                  // (1-cos)/th^2, stable
    } else { alpha = 1.f - th2/6.f; beta = 0.5f; }
    pb[968] = cosf(th);
    pb[969] = alpha;
    pb[970] = beta;
  }
}

// ---------------- kernel 2: circuit simulation -> out = U (raw) ----------------
// Grid: blockIdx = cb*64 + s (output 64B-line pairs land on the same XCD).
// Block 512 thr = 8 waves, one wave per column, st[wid] wave-private ->
// no barriers in the layer loop. Rotation coeffs/B-phases are wave-uniform
// (SGPR); A-phase is a per-lane float2 load.
__global__ __launch_bounds__(512, 8)
void sim_kernel(const float* __restrict__ prep, float* __restrict__ out){
  __shared__ __align__(16) float2 st[8][512];
  const int s    = blockIdx.x & 63;
  const int cb   = blockIdx.x >> 6;
  const int wid  = threadIdx.x >> 6;
  const int lane = threadIdx.x & 63;
  const int col  = cb*8 + wid;               // input basis state / U column
  const float* gp = prep + s*1024;
  float2* const S = st[wid];
  const float2 NEG1P1 = make_float2(-1.f, 1.f);

  float2 amp[8];
  // ---- layer 1 on basis state |col> : product state, O(D) ----
  {
    float2 base = make_float2(1.f, 0.f);
    #pragma unroll
    for (int w = 0; w < 6; ++w){
      const int xb = (lane >> (5 - w)) & 1;  // x bit 8-w  (lane = x>>3)
      const int ib = (col  >> (8 - w)) & 1;  // input bit of wire w
      const float2 ge = *(const float2*)(gp + 8*w + (xb*2 + ib)*2);
      base = cmul(base, ge);
    }
    const int i6 = (col >> 2) & 1, i7 = (col >> 1) & 1, i8 = col & 1;
    float2 G6[2], G7[2], G8[2];
    #pragma unroll
    for (int r = 0; r < 2; ++r){
      G6[r] = *(const float2*)(gp + 8*6 + (r*2 + i6)*2);
      G7[r] = *(const float2*)(gp + 8*7 + (r*2 + i7)*2);
      G8[r] = *(const float2*)(gp + 8*8 + (r*2 + i8)*2);
    }
    #pragma unroll
    for (int j = 0; j < 8; ++j){
      const float2 tj = cmul(cmul(G6[(j>>2)&1], G7[(j>>1)&1]), G8[j&1]);
      amp[j] = cmul(base, tj);
    }
    // write with ring-1 folded: element x = 8*lane + j -> slot phys(F(x))
    const int bFI = physmap(Fperm(lane << 3));
    #pragma unroll
    for (int j = 0; j < 8; ++j) S[bFI ^ physmap(Fperm(j))] = amp[j];
  }

  const int base1 = (lane << 3) ^ ((lane >> 1) & 15);            // phys(8*lane)
  const int hq = lane >> 3, lq = lane & 7;
  const int base2 = (hq << 6) ^ ((hq << 2) & 15) ^ lq;           // phys(64h)^l
  const int base3 = lane ^ (lane >> 4);                          // phys(lane)
  const int baseF = physmap(Fperm(lane));

  #pragma unroll
  for (int L = 0; L < 3; ++L){
    const float* lb = gp + 128 + L*256;
    // round 1: wires 6,7,8 (x bits 2..0) — linear read (ring already folded)
    #pragma unroll
    for (int j = 0; j < 8; ++j) amp[j] = S[base1 ^ j];
    apply_rot<4>(amp, (const float2*)(lb + 6*4));    // wire 6 (bit 2)
    apply_rot<2>(amp, (const float2*)(lb + 7*4));    // wire 7 (bit 1)
    apply_rot<1>(amp, (const float2*)(lb + 8*4));    // wire 8 (bit 0)
    #pragma unroll
    for (int j = 0; j < 8; ++j) S[base1 ^ j] = amp[j];
    // round 2: wires 3,4,5 (x bits 5..3); x = 64h + 8j + l
    #pragma unroll
    for (int j = 0; j < 8; ++j) amp[j] = S[base2 ^ ((j << 3) ^ (j >> 1))];
    apply_rot<4>(amp, (const float2*)(lb + 3*4));    // wire 3 (bit 5)
    apply_rot<2>(amp, (const float2*)(lb + 4*4));    // wire 4 (bit 4)
    apply_rot<1>(amp, (const float2*)(lb + 5*4));    // wire 5 (bit 3)
    #pragma unroll
    for (int j = 0; j < 8; ++j) S[base2 ^ ((j << 3) ^ (j >> 1))] = amp[j];
    // round 3: wires 0,1,2 (x bits 8..6); x = 64j + lane
    #pragma unroll
    for (int j = 0; j < 8; ++j) amp[j] = S[base3 ^ ((j << 6) ^ ((4*j) & 15))];
    apply_rot<4>(amp, (const float2*)(lb + 0*4));    // wire 0 (bit 8)
    apply_rot<2>(amp, (const float2*)(lb + 1*4));    // wire 1 (bit 7)
    apply_rot<1>(amp, (const float2*)(lb + 2*4));    // wire 2 (bit 6)
    // deferred diagonal phase: D(x) = B[j] * A[lane], x = 64j + lane
    {
      const float2 A = *(const float2*)(lb + 128 + lane*2);
      #pragma unroll
      for (int j = 0; j < 8; ++j){
        const float2 P = *(const float2*)(lb + 64 + j*4);
        const float2 Q = *(const float2*)(lb + 64 + j*4 + 2);
        const float2 C = pk_fma_vs_lo(A, P, pk_mul_vs_hi(A, Q));  // A*B[j]
        const float2 Dn = pk_swapneg(C, NEG1P1);                  // (-Cy, Cx)
        amp[j] = pk_fma_vv_lo(amp[j], C, pk_mul_vv_hi(amp[j], Dn));
      }
    }
    // write with this layer's ring folded: x = 64j + lane -> phys(F(x))
    #pragma unroll
    for (int j = 0; j < 8; ++j) S[baseF ^ physmap(Fperm(j << 6))] = amp[j];
  }

  __syncthreads();                            // output reads other waves' arrays
  // transposed write of Re(state); state fully permuted -> linear element a.
  #pragma unroll
  for (int rep = 0; rep < 2; ++rep){
    const int a  = (threadIdx.x >> 1) + rep*256;
    const int q  = threadIdx.x & 1;
    const int pa = a ^ ((a >> 4) & 15);
    float4 vv;
    vv.x = st[q*4 + 0][pa].x;
    vv.y = st[q*4 + 1][pa].x;
    vv.z = st[q*4 + 2][pa].x;
    vv.w = st[q*4 + 3][pa].x;
    *(float4*)&out[(size_t)s*262144 + (size_t)a*512 + cb*8 + q*4] = vv;
  }
}

// ---------------- kernel 3: rank-2 expm correction on cols 0..71 ----------------
// out[:,0]   = cos(th)*u0 - alpha*(U v)
// out[:,j]   = U[:,j] + (alpha*u0 - beta*(U v)) * v[j]   (1<=j<72)
// Grid: 64 samples x 32 row-groups of 16 rows; thread = (row, float4-quad).
__global__ __launch_bounds__(288)
void corr_kernel(const float* __restrict__ prep, float* __restrict__ out){
  __shared__ float part[16][18];
  __shared__ float srow[16][2];               // [0]=w, [1]=new col0 value
  const int s  = blockIdx.x >> 5;
  const int rg = blockIdx.x & 31;
  const float* pp = prep + s*1024;
  const int lr = threadIdx.x / 18;            // 0..15
  const int q  = threadIdx.x - lr*18;         // 0..17
  float* rowp = out + (size_t)s*262144 + (size_t)(rg*16 + lr)*512;
  const float4 x  = *(const float4*)(rowp + q*4);
  const float4 vv = *(const float4*)(pp + 896 + q*4);
  part[lr][q] = fmaf(x.x,vv.x, fmaf(x.y,vv.y, fmaf(x.z,vv.z, x.w*vv.w)));
  __syncthreads();
  if (threadIdx.x < 16){
    const int row = threadIdx.x;
    float uv = 0.f;
    #pragma unroll
    for (int k = 0; k < 18; ++k) uv += part[row][k];
    const float u0 = out[(size_t)s*262144 + (size_t)(rg*16 + row)*512];
    const float cth = pp[968], alpha = pp[969], beta = pp[970];
    srow[row][0] = fmaf(alpha, u0, -beta*uv);
    srow[row][1] = cth*u0 - alpha*uv;
  }
  __syncthreads();
  const float w = srow[lr][0];
  float4 o;
  o.x = fmaf(w, vv.x, x.x); o.y = fmaf(w, vv.y, x.y);
  o.z = fmaf(w, vv.z, x.z); o.w = fmaf(w, vv.w, x.w);
  if (q == 0) o.x = srow[lr][1];              // v[0]=0, so fma left x.x; replace
  *(float4*)(rowp + q*4) = o;
}

extern "C" void kernel_launch(void* const* d_in, const int* in_sizes, int n_in,
                              void* d_out, int out_size, void* d_ws, size_t ws_size,
                              hipStream_t stream){
  const float* t  = (const float*)d_in[0];
  const float* w1 = (const float*)d_in[1];
  const float* b1 = (const float*)d_in[2];
  const float* w2 = (const float*)d_in[3];
  const float* b2 = (const float*)d_in[4];
  float* out  = (float*)d_out;
  float* prep = (float*)d_ws;                 // 64*1024 floats = 256 KiB used
  prep_kernel<<<64,   576, 0, stream>>>(t, w1, b1, w2, b2, prep);
  sim_kernel <<<4096, 512, 0, stream>>>(prep, out);
  corr_kernel<<<2048, 288, 0, stream>>>(prep, out);
}